// Round 7
// baseline (426.387 us; speedup 1.0000x reference)
//
#include <hip/hip_runtime.h>

#define CLIPV 100000.0f
typedef __attribute__((address_space(3))) void as3void;
typedef __attribute__((address_space(1))) void as1void;

__device__ __forceinline__ float fexp2(float x){ return __builtin_amdgcn_exp2f(x); }
__device__ __forceinline__ float frcp(float x){ return __builtin_amdgcn_rcpf(x); }

#define WAIT_VM(N) { asm volatile("s_waitcnt vmcnt(" #N ")" ::: "memory"); \
                     __builtin_amdgcn_sched_barrier(0); }
#define LGKM0_BAR() { asm volatile("s_waitcnt lgkmcnt(0)" ::: "memory"); \
                      __builtin_amdgcn_s_barrier(); }

struct PC {
    float smax_s, qmax_s, ddf5, tmax3, k10, ism, cw, Kc, cf, k1m;
};

__device__ __forceinline__ PC make_pc(const float* fpar, const float* smaxp,
                                      const float* qmaxp, const float* ddfp,
                                      const float* tminp, const float* tmaxp,
                                      const float* kp)
{
    PC P;
    float f10    = fpar[0] * 0.1f;
    P.smax_s = smaxp[0] * 1500.0f;
    P.qmax_s = qmaxp[0] * 50.0f;
    P.ddf5   = ddfp[0] * 5.0f;
    float tmin_s = tminp[0] * -3.0f;
    P.tmax3  = tmaxp[0] * 3.0f;
    P.k10    = kp[0] * 0.1f;
    P.ism    = 1.0f / P.smax_s;
    P.cw     = 14.426950408889634f * tmin_s;
    P.Kc     = fexp2(14.426950408889634f * (P.tmax3 - tmin_s));
    P.cf     = 1.4426950408889634f * f10;
    P.k1m    = 1.0f - P.k10;
    return P;
}

// The consumer recurrence step — identical math in probe and real kernel.
__device__ __forceinline__ void chain_step(const PC& P,
        float prain, float psnow, float pet, float eg1, float tmg,
        float& s0v, float& s1v, float& qq, float& c_et,
        float& oqq, float& oqb)
{
    const float NL = -14.426950408889634f;
    float es0 = fexp2(NL * s0v);
    float hg  = frcp(fmaf(es0, eg1, eg1));
    float m   = hg * fminf(s0v, tmg);
    float ds0 = psnow - m;
    s0v += fminf(fmaxf(ds0, -CLIPV), CLIPV);
    float et  = c_et * pet;
    float pme = (prain + m) - et;
    float ds1 = pme - qq;
    s1v += fminf(fmaxf(ds1, -CLIPV), CLIPV);
    float d   = s1v - P.smax_s;
    float eo  = fminf(fexp2(NL * d), 1e30f);
    float e   = fexp2(P.cf * d);
    float ep  = fminf(fexp2(NL * s1v), 1e30f);
    float den = (1.0f + ep) * (1.0f + eo);
    float hpo = frcp(den);
    float w1  = fmaf(e, eo, 1.0f);
    float qmw = P.qmax_s * w1;
    qq   = hpo * (d + qmw);
    oqb  = hpo * qmw;
    oqq  = qq;
    c_et = hpo * fmaf(eo, s1v * P.ism, 1.0f);
}

__device__ __forceinline__ void init_chain(const PC& P, float& qq, float& c_et)
{
    const float NL = -14.426950408889634f;
    float d   = -P.smax_s;
    float eo  = fminf(fexp2(NL * d), 1e30f);
    float den = 2.0f * (1.0f + eo);
    float hpo = frcp(den);
    float e   = fexp2(P.cf * d);
    float w1  = fmaf(e, eo, 1.0f);
    qq   = hpo * fmaf(P.qmax_s, w1, d);
    c_et = hpo;
}

// ======================= PROBE A: chain only =======================
// 1024 steps of the exact consumer recurrence, pure registers, no LDS,
// no barriers, synthesized in-range inputs. Writes to d_out (overwritten
// later by the real kernel).
extern "C" __global__ void __launch_bounds__(64, 1)
probe_chain(const float* __restrict__ fpar,  const float* __restrict__ smaxp,
            const float* __restrict__ qmaxp, const float* __restrict__ ddfp,
            const float* __restrict__ tminp, const float* __restrict__ tmaxp,
            const float* __restrict__ kp,
            float* __restrict__ outp)
{
    PC P = make_pc(fpar, smaxp, qmaxp, ddfp, tminp, tmaxp, kp);
    const int gid = blockIdx.x * 64 + threadIdx.x;

    float s0v = 0.0f, s1v = 0.0f, qq, c_et;
    init_chain(P, qq, c_et);

    float xp  = 0.1f + (float)gid * 1e-5f;
    float acc = 0.0f;
    for (int i = 0; i < 64; ++i) {
        #pragma unroll
        for (int u = 0; u < 16; ++u) {
            xp += 0.6180339887f;
            xp -= truncf(xp);                       // keep in [0,1)
            float prain = 2.0f + xp;
            float psnow = 1.5f - 0.5f * xp;
            float pet   = 3.0f + xp;
            float eg1   = 1.2f + 0.3f * xp;
            float tmg   = 4.0f + 2.0f * xp;
            float oqq, oqb;
            chain_step(P, prain, psnow, pet, eg1, tmg, s0v, s1v, qq, c_et, oqq, oqb);
            acc += oqq + oqb;
        }
    }
    outp[gid] = acc;   // keep everything live; overwritten by real kernel
}

// ======================= PROBE B: producer only =======================
// Exact producer path (staging + state-free math + writeback). Consumer wave
// only matches barriers. Writes to d_out (overwritten by real kernel).
extern "C" __global__ void __launch_bounds__(128, 1)
probe_prod(const float* __restrict__ inp,
           const float* __restrict__ fpar,  const float* __restrict__ smaxp,
           const float* __restrict__ qmaxp, const float* __restrict__ ddfp,
           const float* __restrict__ tminp, const float* __restrict__ tmaxp,
           const float* __restrict__ kp,
           float* __restrict__ out)
{
    __shared__ alignas(16) unsigned char lin[2][13312];
    __shared__ alignas(16) float prodb[2][64 * 84];
    __shared__ alignas(16) float lcons[2][64 * 36];

    const int tid = threadIdx.x;
    const int l   = tid & 63;
    const int wv  = tid >> 6;
    const int c0  = blockIdx.x * 64;

    PC P = make_pc(fpar, smaxp, qmaxp, ddfp, tminp, tmaxp, kp);
    const float NL = -14.426950408889634f;

    const float* gin  = inp + (size_t)c0 * 3072;
    float*       gout = out + (size_t)c0 * 2048;

    if (wv == 1) {
        auto stage_load = [&](int s, int pb) {
            const float* gb = gin + s * 48;
            #pragma unroll
            for (int k2 = 0; k2 < 13; ++k2) {
                unsigned e = (unsigned)(k2 * 64 + l);
                unsigned r = (e * 161321u) >> 21;
                int q = (int)(e - r * 13u);
                q = (q > 11) ? 11 : q;
                const float* g = gb + r * 3072 + q * 4;
                __builtin_amdgcn_global_load_lds((as1void*)g,
                    (as3void*)(&lin[pb][k2 * 1024]), 16, 0, 0);
            }
        };
        auto prod_one = [&](float p, float tm, float dl,
                            float& pr, float& ps, float& pe, float& eg, float& tg) {
            float t1 = tm + 237.3f, t2 = tm + 273.2f;
            float r12 = frcp(t1 * t2);
            float e1  = fexp2(24.958624207f * tm * (r12 * t2));
            pe = 436.9872f * dl * e1 * (r12 * t1);
            float ew = fexp2(fmaf(NL, tm, P.cw));
            float w  = frcp(1.0f + ew);
            pr = w * p;
            ps = p - pr;
            eg = 1.0f + fminf(ew * P.Kc, 1e30f);
            tg = P.ddf5 * (tm - P.tmax3);
        };
        auto prod_compute = [&](int s) {
            const unsigned char* myrow = &lin[s & 1][l * 208];
            float* o = prodb[s & 1] + l * 84;
            #pragma unroll
            for (int u4 = 0; u4 < 4; ++u4) {
                float4 A = *(const float4*)(myrow + u4 * 48);
                float4 B = *(const float4*)(myrow + u4 * 48 + 16);
                float4 C = *(const float4*)(myrow + u4 * 48 + 32);
                float pr[4], ps[4], pe[4], eg[4], tg[4];
                prod_one(A.x, A.y, A.z, pr[0], ps[0], pe[0], eg[0], tg[0]);
                prod_one(A.w, B.x, B.y, pr[1], ps[1], pe[1], eg[1], tg[1]);
                prod_one(B.z, B.w, C.x, pr[2], ps[2], pe[2], eg[2], tg[2]);
                prod_one(C.y, C.z, C.w, pr[3], ps[3], pe[3], eg[3], tg[3]);
                *(float4*)(o +      u4 * 4) = make_float4(pr[0], pr[1], pr[2], pr[3]);
                *(float4*)(o + 16 + u4 * 4) = make_float4(ps[0], ps[1], ps[2], ps[3]);
                *(float4*)(o + 32 + u4 * 4) = make_float4(pe[0], pe[1], pe[2], pe[3]);
                *(float4*)(o + 48 + u4 * 4) = make_float4(eg[0], eg[1], eg[2], eg[3]);
                *(float4*)(o + 64 + u4 * 4) = make_float4(tg[0], tg[1], tg[2], tg[3]);
            }
        };
        auto writeback = [&](int s) {
            float* gb = gout + s * 32;
            const float* lc = lcons[s & 1];
            #pragma unroll
            for (int k2 = 0; k2 < 9; ++k2) {
                unsigned e = (unsigned)(k2 * 64 + l);
                unsigned r = (e * 233017u) >> 21;
                int q = (int)(e - r * 9u);
                if (q < 8) {
                    const float* p0 = lc + r * 36 + 2 * q;
                    float2 qqv = *(const float2*)(p0);
                    float2 qbv = *(const float2*)(p0 + 16);
                    float o1a = P.k1m * qbv.x, o1b = P.k1m * qbv.y;
                    float4 v = make_float4(qqv.x - o1a, o1a, qqv.y - o1b, o1b);
                    *(float4*)(gb + r * 2048 + q * 4) = v;
                }
            }
        };

        stage_load(0, 0);
        WAIT_VM(0);
        stage_load(1, 1);
        prod_compute(0);
        LGKM0_BAR();
        stage_load(2, 0);
        WAIT_VM(13);
        prod_compute(1);
        LGKM0_BAR();
        for (int i = 2; i <= 62; ++i) {
            writeback(i - 2);
            stage_load(i + 1, (i + 1) & 1);
            WAIT_VM(22);
            prod_compute(i);
            LGKM0_BAR();
        }
        writeback(61);
        WAIT_VM(9);
        prod_compute(63);
        LGKM0_BAR();
        writeback(62);
        LGKM0_BAR();
        writeback(63);
    } else {
        // idle consumer: zero lcons once (avoid NaN/denorm pathology in
        // writeback reads), then match the producer's 65 barriers.
        float* z = (float*)lcons;
        #pragma unroll
        for (int i = 0; i < 72; ++i) z[i * 64 + l] = 0.0f;
        for (int i = 0; i < 65; ++i) LGKM0_BAR();
    }
}

// ======================= REAL KERNEL (R6, unchanged) =======================
extern "C" __global__ void __launch_bounds__(128, 1)
prnn_kernel(const float* __restrict__ inp,
            const float* __restrict__ fpar,  const float* __restrict__ smaxp,
            const float* __restrict__ qmaxp, const float* __restrict__ ddfp,
            const float* __restrict__ tminp, const float* __restrict__ tmaxp,
            const float* __restrict__ kp,
            float* __restrict__ out)
{
    __shared__ alignas(16) unsigned char lin[2][13312];
    __shared__ alignas(16) float prodb[2][64 * 84];
    __shared__ alignas(16) float lcons[2][64 * 36];

    const int tid = threadIdx.x;
    const int l   = tid & 63;
    const int wv  = tid >> 6;
    const int c0  = blockIdx.x * 64;

    PC P = make_pc(fpar, smaxp, qmaxp, ddfp, tminp, tmaxp, kp);
    const float NL = -14.426950408889634f;

    const float* gin  = inp + (size_t)c0 * 3072;
    float*       gout = out + (size_t)c0 * 2048;

    if (wv == 1) {
        auto stage_load = [&](int s, int pb) {
            const float* gb = gin + s * 48;
            #pragma unroll
            for (int k2 = 0; k2 < 13; ++k2) {
                unsigned e = (unsigned)(k2 * 64 + l);
                unsigned r = (e * 161321u) >> 21;
                int q = (int)(e - r * 13u);
                q = (q > 11) ? 11 : q;
                const float* g = gb + r * 3072 + q * 4;
                __builtin_amdgcn_global_load_lds((as1void*)g,
                    (as3void*)(&lin[pb][k2 * 1024]), 16, 0, 0);
            }
        };
        auto prod_one = [&](float p, float tm, float dl,
                            float& pr, float& ps, float& pe, float& eg, float& tg) {
            float t1 = tm + 237.3f, t2 = tm + 273.2f;
            float r12 = frcp(t1 * t2);
            float e1  = fexp2(24.958624207f * tm * (r12 * t2));
            pe = 436.9872f * dl * e1 * (r12 * t1);
            float ew = fexp2(fmaf(NL, tm, P.cw));
            float w  = frcp(1.0f + ew);
            pr = w * p;
            ps = p - pr;
            eg = 1.0f + fminf(ew * P.Kc, 1e30f);
            tg = P.ddf5 * (tm - P.tmax3);
        };
        auto prod_compute = [&](int s) {
            const unsigned char* myrow = &lin[s & 1][l * 208];
            float* o = prodb[s & 1] + l * 84;
            #pragma unroll
            for (int u4 = 0; u4 < 4; ++u4) {
                float4 A = *(const float4*)(myrow + u4 * 48);
                float4 B = *(const float4*)(myrow + u4 * 48 + 16);
                float4 C = *(const float4*)(myrow + u4 * 48 + 32);
                float pr[4], ps[4], pe[4], eg[4], tg[4];
                prod_one(A.x, A.y, A.z, pr[0], ps[0], pe[0], eg[0], tg[0]);
                prod_one(A.w, B.x, B.y, pr[1], ps[1], pe[1], eg[1], tg[1]);
                prod_one(B.z, B.w, C.x, pr[2], ps[2], pe[2], eg[2], tg[2]);
                prod_one(C.y, C.z, C.w, pr[3], ps[3], pe[3], eg[3], tg[3]);
                *(float4*)(o +      u4 * 4) = make_float4(pr[0], pr[1], pr[2], pr[3]);
                *(float4*)(o + 16 + u4 * 4) = make_float4(ps[0], ps[1], ps[2], ps[3]);
                *(float4*)(o + 32 + u4 * 4) = make_float4(pe[0], pe[1], pe[2], pe[3]);
                *(float4*)(o + 48 + u4 * 4) = make_float4(eg[0], eg[1], eg[2], eg[3]);
                *(float4*)(o + 64 + u4 * 4) = make_float4(tg[0], tg[1], tg[2], tg[3]);
            }
        };
        auto writeback = [&](int s) {
            float* gb = gout + s * 32;
            const float* lc = lcons[s & 1];
            #pragma unroll
            for (int k2 = 0; k2 < 9; ++k2) {
                unsigned e = (unsigned)(k2 * 64 + l);
                unsigned r = (e * 233017u) >> 21;
                int q = (int)(e - r * 9u);
                if (q < 8) {
                    const float* p0 = lc + r * 36 + 2 * q;
                    float2 qqv = *(const float2*)(p0);
                    float2 qbv = *(const float2*)(p0 + 16);
                    float o1a = P.k1m * qbv.x, o1b = P.k1m * qbv.y;
                    float4 v = make_float4(qqv.x - o1a, o1a, qqv.y - o1b, o1b);
                    *(float4*)(gb + r * 2048 + q * 4) = v;
                }
            }
        };

        stage_load(0, 0);
        WAIT_VM(0);
        stage_load(1, 1);
        prod_compute(0);
        LGKM0_BAR();
        stage_load(2, 0);
        WAIT_VM(13);
        prod_compute(1);
        LGKM0_BAR();
        for (int i = 2; i <= 62; ++i) {
            writeback(i - 2);
            stage_load(i + 1, (i + 1) & 1);
            WAIT_VM(22);
            prod_compute(i);
            LGKM0_BAR();
        }
        writeback(61);
        WAIT_VM(9);
        prod_compute(63);
        LGKM0_BAR();
        writeback(62);
        LGKM0_BAR();
        writeback(63);
    } else {
        float s0v = 0.0f, s1v = 0.0f, qq, c_et;
        init_chain(P, qq, c_et);
        LGKM0_BAR();
        for (int i = 1; i <= 64; ++i) {
            const int sb = (i - 1) & 1;
            const float* base = prodb[sb] + l * 84;
            float4 PR[5][4];
            #pragma unroll
            for (int q = 0; q < 5; ++q) {
                #pragma unroll
                for (int g = 0; g < 4; ++g)
                    PR[q][g] = *(const float4*)(base + q * 16 + g * 4);
            }
            float* lcb = lcons[sb] + l * 36;
            #pragma unroll
            for (int g = 0; g < 4; ++g) {
                float qs[4], qb[4];
                chain_step(P, PR[0][g].x, PR[1][g].x, PR[2][g].x, PR[3][g].x, PR[4][g].x,
                           s0v, s1v, qq, c_et, qs[0], qb[0]);
                chain_step(P, PR[0][g].y, PR[1][g].y, PR[2][g].y, PR[3][g].y, PR[4][g].y,
                           s0v, s1v, qq, c_et, qs[1], qb[1]);
                chain_step(P, PR[0][g].z, PR[1][g].z, PR[2][g].z, PR[3][g].z, PR[4][g].z,
                           s0v, s1v, qq, c_et, qs[2], qb[2]);
                chain_step(P, PR[0][g].w, PR[1][g].w, PR[2][g].w, PR[3][g].w, PR[4][g].w,
                           s0v, s1v, qq, c_et, qs[3], qb[3]);
                *(float4*)(lcb +      g * 4) = make_float4(qs[0], qs[1], qs[2], qs[3]);
                *(float4*)(lcb + 16 + g * 4) = make_float4(qb[0], qb[1], qb[2], qb[3]);
            }
            LGKM0_BAR();
        }
    }
}

extern "C" void kernel_launch(void* const* d_in, const int* in_sizes, int n_in,
                              void* d_out, int out_size, void* d_ws, size_t ws_size,
                              hipStream_t stream) {
    const float* inp = (const float*)d_in[0];
    const int B = in_sizes[0] / 3072;   // T=1024, 3 features
    const float* f_    = (const float*)d_in[1];
    const float* smax_ = (const float*)d_in[2];
    const float* qmax_ = (const float*)d_in[3];
    const float* ddf_  = (const float*)d_in[4];
    const float* tmin_ = (const float*)d_in[5];
    const float* tmax_ = (const float*)d_in[6];
    const float* k_    = (const float*)d_in[7];
    float* outp = (float*)d_out;

    // Ablation probes (write into d_out, fully overwritten by the real kernel).
    probe_chain<<<B / 64, 64, 0, stream>>>(f_, smax_, qmax_, ddf_, tmin_, tmax_, k_, outp);
    probe_prod<<<B / 64, 128, 0, stream>>>(inp, f_, smax_, qmax_, ddf_, tmin_, tmax_, k_, outp);
    // Real kernel (R6 structure) — produces the final, correct output.
    prnn_kernel<<<B / 64, 128, 0, stream>>>(inp, f_, smax_, qmax_, ddf_, tmin_, tmax_, k_, outp);
}

// Round 9
// 247.004 us; speedup vs baseline: 1.7262x; 1.7262x over previous
//
#include <hip/hip_runtime.h>

typedef __attribute__((address_space(3))) void as3void;
typedef __attribute__((address_space(1))) void as1void;

__device__ __forceinline__ float fexp2(float x){ return __builtin_amdgcn_exp2f(x); }
__device__ __forceinline__ float frcp(float x){ return __builtin_amdgcn_rcpf(x); }

#define WAIT_VM0() { asm volatile("s_waitcnt vmcnt(0)" ::: "memory"); \
                     __builtin_amdgcn_sched_barrier(0); }
#define LGKM0_BAR() { asm volatile("s_waitcnt lgkmcnt(0)" ::: "memory"); \
                      __builtin_amdgcn_s_barrier(); }

// 64 chains/block, 3 waves: wv0 = consumer (serial recurrence, short chain),
// wv1/wv2 = producers (split staging + state-free math + pure-copy writeback).
// Slot = 16 steps. Skew: producers fill prodb[s] in slot s; consumer runs
// stage s-1 in slot s; producers copy lcons[s-2] out in slot s.
// lin: triple-buffered (stage s+2 issued in slot s). prodb row: [5 quant][16 steps].
// lcons row: 16 steps x (o0,o1) interleaved = 32 floats (+4 pad).
extern "C" __global__ void __launch_bounds__(192, 1)
prnn_kernel(const float* __restrict__ inp,
            const float* __restrict__ fpar,  const float* __restrict__ smaxp,
            const float* __restrict__ qmaxp, const float* __restrict__ ddfp,
            const float* __restrict__ tminp, const float* __restrict__ tmaxp,
            const float* __restrict__ kp,
            float* __restrict__ out)
{
    __shared__ alignas(16) unsigned char lin[3][13312];   // 3 x 64 rows x 13 x 16B
    __shared__ alignas(16) float prodb[2][64 * 84];       // 2 x 21504 B
    __shared__ alignas(16) float lcons[2][64 * 36];       // 2 x 9216 B

    const int tid = threadIdx.x;
    const int l   = tid & 63;
    const int wv  = tid >> 6;
    const int c0  = blockIdx.x * 64;

    const float NL = -14.426950408889634f;   // -10*log2(e)
    float f10    = fpar[0] * 0.1f;
    float smax_s = smaxp[0] * 1500.0f;
    float qmax_s = qmaxp[0] * 50.0f;
    float ddf5   = ddfp[0] * 5.0f;
    float tmin_s = tminp[0] * -3.0f;
    float tmax3  = tmaxp[0] * 3.0f;
    float k10    = kp[0] * 0.1f;
    float ism    = 1.0f / smax_s;
    float cw     = 14.426950408889634f * tmin_s;
    float Kc     = fexp2(14.426950408889634f * (tmax3 - tmin_s));
    float cf     = 1.4426950408889634f * f10;
    float k1m    = 1.0f - k10;
    float C1     = 14.426950408889634f * smax_s;   // -NL*smax
    float C2     = -cf * smax_s;

    const float* gin  = inp + (size_t)c0 * 3072;
    float*       gout = out + (size_t)c0 * 2048;

    if (wv >= 1) {
        // ========================= PRODUCERS =========================
        const int pidx = wv - 1;

        auto stage_load = [&](int s) {      // 13 x global_load_lds(16B), one wave
            const float* gb = gin + s * 48;
            unsigned char* lb = lin[s % 3];
            #pragma unroll
            for (int k2 = 0; k2 < 13; ++k2) {
                unsigned e = (unsigned)(k2 * 64 + l);
                unsigned r = (e * 161321u) >> 21;      // e/13 (e<832)
                int q = (int)(e - r * 13u);
                q = (q > 11) ? 11 : q;                 // pad unit -> dummy
                const float* g = gb + r * 3072 + q * 4;
                __builtin_amdgcn_global_load_lds((as1void*)g,
                    (as3void*)(lb + k2 * 1024), 16, 0, 0);
            }
        };

        auto prod_one = [&](float p, float tm, float dl,
                            float& pr, float& ps, float& pe, float& eg, float& tg) {
            float t1 = tm + 237.3f, t2 = tm + 273.2f;
            float r12 = frcp(t1 * t2);
            float e1  = fexp2(24.958624207f * tm * (r12 * t2));
            pe = 436.9872f * dl * e1 * (r12 * t1);
            float ew = fexp2(fmaf(NL, tm, cw));        // exp(-10(tm - tmin_s))
            float w  = frcp(1.0f + ew);
            pr = w * p;
            ps = p - pr;
            eg = 1.0f + fminf(ew * Kc, 1e30f);         // 1 + exp(-10(tm - tmax3))
            tg = ddf5 * (tm - tmax3);
        };

        auto prod_half = [&](int s) {       // this wave: steps pidx*8 .. pidx*8+7
            const unsigned char* myrow = lin[s % 3] + l * 208 + pidx * 96;
            float* o = prodb[s & 1] + l * 84 + pidx * 8;
            #pragma unroll
            for (int g2 = 0; g2 < 2; ++g2) {
                float4 A = *(const float4*)(myrow + g2 * 48);
                float4 B = *(const float4*)(myrow + g2 * 48 + 16);
                float4 C = *(const float4*)(myrow + g2 * 48 + 32);
                float pr[4], ps[4], pe[4], eg[4], tg[4];
                prod_one(A.x, A.y, A.z, pr[0], ps[0], pe[0], eg[0], tg[0]);
                prod_one(A.w, B.x, B.y, pr[1], ps[1], pe[1], eg[1], tg[1]);
                prod_one(B.z, B.w, C.x, pr[2], ps[2], pe[2], eg[2], tg[2]);
                prod_one(C.y, C.z, C.w, pr[3], ps[3], pe[3], eg[3], tg[3]);
                *(float4*)(o +      g2 * 4) = make_float4(pr[0], pr[1], pr[2], pr[3]);
                *(float4*)(o + 16 + g2 * 4) = make_float4(ps[0], ps[1], ps[2], ps[3]);
                *(float4*)(o + 32 + g2 * 4) = make_float4(pe[0], pe[1], pe[2], pe[3]);
                *(float4*)(o + 48 + g2 * 4) = make_float4(eg[0], eg[1], eg[2], eg[3]);
                *(float4*)(o + 64 + g2 * 4) = make_float4(tg[0], tg[1], tg[2], tg[3]);
            }
        };

        auto wb_half = [&](int j) {         // pure copy LDS->global, 4 units/lane
            const float* lc = lcons[j & 1];
            float* gb = gout + j * 32;
            #pragma unroll
            for (int i = 0; i < 4; ++i) {
                int u = pidx * 256 + i * 64 + l;   // 0..511
                int r = u >> 3, q = u & 7;
                float4 v = *(const float4*)(lc + r * 36 + q * 4);
                *(float4*)(gb + (size_t)r * 2048 + q * 4) = v;
            }
        };

        // prologue: stage 0 (wave A) + stage 1 (wave B); A drains stage 0.
        if (pidx == 0) { stage_load(0); WAIT_VM0(); }
        else           { stage_load(1); }
        LGKM0_BAR();

        for (int s = 0; s <= 65; ++s) {
            if (s <= 61 && pidx == (s & 1))       stage_load(s + 2);
            if (s <= 63)                          prod_half(s);
            if (s >= 2)                           wb_half(s - 2);
            if (s <= 62 && pidx == ((s + 1) & 1)) WAIT_VM0();   // drain stage s+1
            LGKM0_BAR();
        }
    } else {
        // ========================= CONSUMER =========================
        float s0 = 0.0f, s1 = 0.0f;

        // Per-step: soil terms at START-of-step s1 give (a) this step's drains
        // (matches reference) and (b) outputs of the PREVIOUS step.
        auto STEP = [&](float prain, float psnow, float pet, float eg1, float tmg,
                        float& o0, float& o1) {
            float eo  = fminf(fexp2(fmaf(NL, s1, C1)), 1e30f);  // exp(-10(s1-smax))
            float ep  = fminf(fexp2(NL * s1), 1e30f);           // exp(-10 s1)
            float e   = fexp2(fmaf(cf, s1, C2));                // exp(f10(s1-smax))
            float hpo = frcp((1.0f + ep) * (1.0f + eo));
            float d   = s1 - smax_s;
            float qmw = qmax_s * fmaf(e, eo, 1.0f);
            float W   = d + qmw;
            float Z   = fmaf(eo, s1 * ism, 1.0f);
            float Y   = fmaf(pet, Z, W);        // (et+qq)/hpo
            float qsub = hpo * qmw;
            float qq   = hpo * W;
            o1 = k1m * qsub;                    // qgr
            o0 = qq - o1;                       // qsurf + qst
            float es0 = fexp2(NL * s0);
            float hg  = frcp(fmaf(es0, eg1, eg1));
            float m   = hg * fminf(s0, tmg);
            s0 = (s0 + psnow) - m;              // clip provably never binds
            s1 = fmaf(-hpo, Y, (s1 + prain) + m);
        };
        auto OUTV = [&](float& o0, float& o1) { // boundary output (no state advance)
            float eo  = fminf(fexp2(fmaf(NL, s1, C1)), 1e30f);
            float ep  = fminf(fexp2(NL * s1), 1e30f);
            float e   = fexp2(fmaf(cf, s1, C2));
            float hpo = frcp((1.0f + ep) * (1.0f + eo));
            float d   = s1 - smax_s;
            float qmw = qmax_s * fmaf(e, eo, 1.0f);
            float qsub = hpo * qmw;
            float qq   = hpo * (d + qmw);
            o1 = k1m * qsub;
            o0 = qq - o1;
        };

        LGKM0_BAR();                            // prologue barrier
        for (int s = 0; s <= 65; ++s) {
            if (s >= 1 && s <= 64) {
                const int st = s - 1;
                const float* base = prodb[st & 1] + l * 84;
                float4 PR[5][4];
                #pragma unroll
                for (int q = 0; q < 5; ++q) {
                    #pragma unroll
                    for (int g = 0; g < 4; ++g)
                        PR[q][g] = *(const float4*)(base + q * 16 + g * 4);
                }
                float o0s[16], o1s[16], dum0, dum1;
                #define SGC(g, cx, O0, O1) \
                    STEP(PR[0][g].cx, PR[1][g].cx, PR[2][g].cx, PR[3][g].cx, PR[4][g].cx, O0, O1)
                SGC(0, x, dum0, dum1);          // output of prev slot's last step: already written
                SGC(0, y, o0s[0],  o1s[0]);
                SGC(0, z, o0s[1],  o1s[1]);
                SGC(0, w, o0s[2],  o1s[2]);
                SGC(1, x, o0s[3],  o1s[3]);
                SGC(1, y, o0s[4],  o1s[4]);
                SGC(1, z, o0s[5],  o1s[5]);
                SGC(1, w, o0s[6],  o1s[6]);
                SGC(2, x, o0s[7],  o1s[7]);
                SGC(2, y, o0s[8],  o1s[8]);
                SGC(2, z, o0s[9],  o1s[9]);
                SGC(2, w, o0s[10], o1s[10]);
                SGC(3, x, o0s[11], o1s[11]);
                SGC(3, y, o0s[12], o1s[12]);
                SGC(3, z, o0s[13], o1s[13]);
                SGC(3, w, o0s[14], o1s[14]);
                #undef SGC
                OUTV(o0s[15], o1s[15]);
                (void)dum0; (void)dum1;

                float* lcb = lcons[st & 1] + l * 36;
                #pragma unroll
                for (int j = 0; j < 8; ++j)
                    *(float4*)(lcb + j * 4) =
                        make_float4(o0s[2*j], o1s[2*j], o0s[2*j+1], o1s[2*j+1]);
            }
            LGKM0_BAR();
        }
    }
}

extern "C" void kernel_launch(void* const* d_in, const int* in_sizes, int n_in,
                              void* d_out, int out_size, void* d_ws, size_t ws_size,
                              hipStream_t stream) {
    const float* inp = (const float*)d_in[0];
    const int B = in_sizes[0] / 3072;   // T=1024, 3 features
    prnn_kernel<<<B / 64, 192, 0, stream>>>(
        inp,
        (const float*)d_in[1],  // f
        (const float*)d_in[2],  // smax
        (const float*)d_in[3],  // qmax
        (const float*)d_in[4],  // ddf
        (const float*)d_in[5],  // tmin
        (const float*)d_in[6],  // tmax
        (const float*)d_in[7],  // k
        (float*)d_out);
}